// Round 1
// baseline (539.761 us; speedup 1.0000x reference)
//
#include <hip/hip_runtime.h>

typedef __attribute__((ext_vector_type(4))) float f32x4;
typedef __attribute__((ext_vector_type(8))) short s16x8;
typedef __attribute__((ext_vector_type(4))) unsigned short u16x4;
typedef unsigned short ushortT;

__device__ inline ushortT f2bf(float f) {
  union { float f; unsigned u; } v; v.f = f;
  unsigned r = v.u + 0x7fffu + ((v.u >> 16) & 1u);
  return (ushortT)(r >> 16);
}
__device__ inline float bf2f(ushortT s) {
  union { unsigned u; float f; } v; v.u = ((unsigned)s) << 16;
  return v.f;
}
__device__ inline f32x4 mfma16(s16x8 a, s16x8 b, f32x4 c) {
  return __builtin_amdgcn_mfma_f32_16x16x32_bf16(a, b, c, 0, 0, 0);
}
typedef const __attribute__((address_space(1))) unsigned GU;
typedef __attribute__((address_space(3))) unsigned LU;
__device__ inline void gload_lds16(const void* g, void* l) {
  __builtin_amdgcn_global_load_lds((GU*)g, (LU*)l, 16, 0, 0);
}

// ---------------- prep kernels ----------------
__global__ void conv_bf16(const float* __restrict__ in, ushortT* __restrict__ o) {
  size_t i = ((size_t)blockIdx.x * 256 + threadIdx.x) * 4;
  f32x4 v = *(const f32x4*)(in + i);
  u16x4 u = { f2bf(v[0]), f2bf(v[1]), f2bf(v[2]), f2bf(v[3]) };
  *(u16x4*)(o + i) = u;
}

__global__ void transp_bf16(const float* __restrict__ Wm, ushortT* __restrict__ wt) {
  __shared__ float t[32][33];
  int bx = blockIdx.x, by = blockIdx.y;
  int x = threadIdx.x, y = threadIdx.y;
#pragma unroll
  for (int i = 0; i < 32; i += 8)
    t[y + i][x] = Wm[(size_t)(by * 32 + y + i) * 1024 + bx * 32 + x];
  __syncthreads();
#pragma unroll
  for (int i = 0; i < 32; i += 8)
    wt[(size_t)(bx * 32 + y + i) * 1024 + by * 32 + x] = f2bf(t[x][y + i]);
}

// ---------------- GEMM (C = A @ Bt^T), A:[M,1024] bf16, Bt:[N,1024] bf16 ----------------
// MODE 0: epilogue scatters to q (x0.125), k (B,H,T,D) and vT (B,H,D,T)
// MODE 1: f32 dense output [M,1024]
template <int MODE>
__global__ __launch_bounds__(256) void gemm_bt(const ushortT* __restrict__ A,
                                               const ushortT* __restrict__ Bt,
                                               ushortT* __restrict__ o0,
                                               ushortT* __restrict__ o1,
                                               ushortT* __restrict__ o2,
                                               float* __restrict__ of) {
  __shared__ ushortT lA[128 * 32];
  __shared__ ushortT lB[128 * 32];
  const int tid = threadIdx.x;
  const int w = tid >> 6, l = tid & 63;
  const int a = l & 15, hi = l >> 4;
  const int wr = w >> 1, wc = w & 1;
  const int row0 = blockIdx.y * 128, col0 = blockIdx.x * 128;
  f32x4 acc[4][4] = {};
  const int r1 = tid >> 2, c1 = tid & 3;
  const int r2 = (tid + 256) >> 2, c2 = (tid + 256) & 3;
  for (int k0 = 0; k0 < 1024; k0 += 32) {
    __syncthreads();
    gload_lds16(A + (size_t)(row0 + r1) * 1024 + k0 + c1 * 8, &lA[r1 * 32 + c1 * 8]);
    gload_lds16(A + (size_t)(row0 + r2) * 1024 + k0 + c2 * 8, &lA[r2 * 32 + c2 * 8]);
    gload_lds16(Bt + (size_t)(col0 + r1) * 1024 + k0 + c1 * 8, &lB[r1 * 32 + c1 * 8]);
    gload_lds16(Bt + (size_t)(col0 + r2) * 1024 + k0 + c2 * 8, &lB[r2 * 32 + c2 * 8]);
    __syncthreads();
    s16x8 af[4], bfr[4];
#pragma unroll
    for (int m = 0; m < 4; ++m)
      af[m] = *(const s16x8*)&lA[(wr * 64 + m * 16 + a) * 32 + hi * 8];
#pragma unroll
    for (int n = 0; n < 4; ++n)
      bfr[n] = *(const s16x8*)&lB[(wc * 64 + n * 16 + a) * 32 + hi * 8];
#pragma unroll
    for (int m = 0; m < 4; ++m)
#pragma unroll
      for (int n = 0; n < 4; ++n)
        acc[m][n] = mfma16(af[m], bfr[n], acc[m][n]);
  }
  const int proj = col0 >> 10;
#pragma unroll
  for (int m = 0; m < 4; ++m)
#pragma unroll
    for (int n = 0; n < 4; ++n) {
      const int gr0 = row0 + wr * 64 + m * 16 + hi * 4;
      const int gc = col0 + wc * 64 + n * 16 + a;
#pragma unroll
      for (int r = 0; r < 4; ++r) {
        const int gr = gr0 + r;
        float v = acc[m][n][r];
        if (MODE == 0) {
          const int bb = gr >> 11, t = gr & 2047;
          const int cc = gc & 1023;
          const int hh = cc >> 6, d = cc & 63;
          const size_t bh = (size_t)bb * 16 + hh;
          if (proj == 0)      o0[(bh * 2048 + t) * 64 + d] = f2bf(v * 0.125f);
          else if (proj == 1) o1[(bh * 2048 + t) * 64 + d] = f2bf(v);
          else                o2[(bh * 64 + d) * 2048 + t] = f2bf(v);
        } else {
          of[(size_t)gr * 1024 + gc] = v;
        }
      }
    }
}

// ---------------- fused attention ----------------
#define SBS 2056
__global__ __launch_bounds__(512) void attn_fused(
    const ushortT* __restrict__ qw, const ushortT* __restrict__ kw,
    const ushortT* __restrict__ vtw, const float* __restrict__ sprev,
    const float* __restrict__ alpha, const float* __restrict__ gamma,
    const float* __restrict__ beta, float* __restrict__ raw,
    ushortT* __restrict__ merged) {
  __shared__ ushortT sb[32 * SBS];
  __shared__ float mu_s[32], rs_s[32], li_s[32];
  const int t0 = blockIdx.x * 32;
  const int h = blockIdx.y, b = blockIdx.z;
  const int bh = b * 16 + h;
  const int tid = threadIdx.x;
  const int w = tid >> 6, l = tid & 63;
  const int a = l & 15, hi = l >> 4;
  const int rt = w & 1, cw = w >> 1;

  // Q fragments (rows t0+16rt+a), Q pre-scaled by 1/8
  const ushortT* qrow = qw + ((size_t)bh * 2048 + t0 + 16 * rt + a) * 64;
  s16x8 qf0 = *(const s16x8*)(qrow + hi * 8);
  s16x8 qf1 = *(const s16x8*)(qrow + 32 + hi * 8);

  // phase 1: stream s_prev strip into LDS (bf16) + row stats
  const float* sp = sprev + ((size_t)bh * 2048 + t0) * 2048;
#pragma unroll
  for (int rr = 0; rr < 4; ++rr) {
    const int row = 4 * w + rr;
    const float* rp = sp + (size_t)row * 2048 + 4 * l;
    float sum = 0.f, sq = 0.f;
#pragma unroll
    for (int i = 0; i < 8; ++i) {
      f32x4 v = *(const f32x4*)(rp + 256 * i);
      sum += v[0] + v[1] + v[2] + v[3];
      sq += v[0] * v[0] + v[1] * v[1] + v[2] * v[2] + v[3] * v[3];
      u16x4 u = { f2bf(v[0]), f2bf(v[1]), f2bf(v[2]), f2bf(v[3]) };
      *(u16x4*)&sb[row * SBS + 4 * l + 256 * i] = u;
    }
#pragma unroll
    for (int s = 32; s >= 1; s >>= 1) {
      sum += __shfl_xor(sum, s);
      sq += __shfl_xor(sq, s);
    }
    if (l == 0) {
      float mu = sum * (1.f / 2048.f);
      float var = fmaxf(sq * (1.f / 2048.f) - mu * mu, 0.f);
      mu_s[row] = mu;
      rs_s[row] = 1.f / (sqrtf(var) + 1e-5f);
    }
  }
  const float gate = 1.f / (1.f + __expf(-alpha[h]));
  const float gm = gamma[h], bt = beta[h];
  __syncthreads();

  // phase 2: QK^T + gated norm add, write raw, store masked scores to LDS
  float mu4[4], rs4[4];
#pragma unroll
  for (int r = 0; r < 4; ++r) {
    mu4[r] = mu_s[16 * rt + 4 * hi + r];
    rs4[r] = rs_s[16 * rt + 4 * hi + r];
  }
  const ushortT* kb = kw + (size_t)bh * 2048 * 64;
  float* rawb = raw + ((size_t)bh * 2048 + t0 + 16 * rt) * 2048;
  for (int i = 0; i < 32; ++i) {
    const int col0 = (cw + 4 * i) * 16;
    const ushortT* kr = kb + (size_t)(col0 + a) * 64 + hi * 8;
    s16x8 kf0 = *(const s16x8*)(kr);
    s16x8 kf1 = *(const s16x8*)(kr + 32);
    f32x4 s4 = {};
    s4 = mfma16(qf0, kf0, s4);
    s4 = mfma16(qf1, kf1, s4);
#pragma unroll
    for (int r = 0; r < 4; ++r) {
      const int rl = 16 * rt + 4 * hi + r;
      const float spv = bf2f(sb[rl * SBS + col0 + a]);
      const float rv = s4[r] + gate * (gm * (spv - mu4[r]) * rs4[r] + bt);
      rawb[(size_t)(4 * hi + r) * 2048 + col0 + a] = rv;
      sb[rl * SBS + col0 + a] = f2bf((col0 + a) <= (t0 + rl) ? rv : -1e30f);
    }
  }
  __syncthreads();

  // phase 3: full-row softmax (rows 4w..4w+3), overwrite LDS with exp(S-m)
#pragma unroll
  for (int rr = 0; rr < 4; ++rr) {
    const int row = 4 * w + rr;
    float vals[32];
#pragma unroll
    for (int i = 0; i < 16; ++i) {
      unsigned u = *(const unsigned*)&sb[row * SBS + 2 * l + 128 * i];
      union { unsigned u; float f; } lo, hh;
      lo.u = u << 16; hh.u = u & 0xffff0000u;
      vals[2 * i] = lo.f; vals[2 * i + 1] = hh.f;
    }
    float m = -3e38f;
#pragma unroll
    for (int j = 0; j < 32; ++j) m = fmaxf(m, vals[j]);
#pragma unroll
    for (int s = 32; s >= 1; s >>= 1) m = fmaxf(m, __shfl_xor(m, s));
    float sum = 0.f;
#pragma unroll
    for (int j = 0; j < 32; ++j) { vals[j] = __expf(vals[j] - m); sum += vals[j]; }
#pragma unroll
    for (int s = 32; s >= 1; s >>= 1) sum += __shfl_xor(sum, s);
#pragma unroll
    for (int i = 0; i < 16; ++i) {
      unsigned u = (unsigned)f2bf(vals[2 * i]) | ((unsigned)f2bf(vals[2 * i + 1]) << 16);
      *(unsigned*)&sb[row * SBS + 2 * l + 128 * i] = u;
    }
    if (l == 0) li_s[row] = 1.f / sum;
  }
  __syncthreads();

  // phase 4: PV (wave -> (rt, n) output sub-tile), read P from LDS, V^T from global
  const int n = w >> 1;
  const ushortT* vb = vtw + ((size_t)bh * 64 + 16 * n + a) * 2048;
  f32x4 acc = {};
  const int nch = blockIdx.x + 1;
  for (int c = 0; c < nch; ++c) {
    s16x8 pf = *(const s16x8*)&sb[(16 * rt + a) * SBS + 32 * c + 8 * hi];
    s16x8 vf = *(const s16x8*)(vb + 32 * c + 8 * hi);
    acc = mfma16(pf, vf, acc);
  }
#pragma unroll
  for (int r = 0; r < 4; ++r) {
    const int rl = 16 * rt + 4 * hi + r;
    const float cx = acc[r] * li_s[rl];
    merged[((size_t)b * 2048 + t0 + rl) * 1024 + h * 64 + 16 * n + a] = f2bf(cx);
  }
}

extern "C" void kernel_launch(void* const* d_in, const int* in_sizes, int n_in,
                              void* d_out, int out_size, void* d_ws, size_t ws_size,
                              hipStream_t stream) {
  (void)in_sizes; (void)n_in; (void)out_size; (void)ws_size;
  const float* x      = (const float*)d_in[0];
  const float* s_prev = (const float*)d_in[1];
  const float* Wq     = (const float*)d_in[2];
  const float* Wk     = (const float*)d_in[3];
  const float* Wv     = (const float*)d_in[4];
  const float* Wo     = (const float*)d_in[5];
  const float* alpha  = (const float*)d_in[6];
  const float* gamma  = (const float*)d_in[7];
  const float* beta   = (const float*)d_in[8];

  float* out = (float*)d_out;
  float* raw = out + (size_t)4194304;  // B*T*HID

  char* ws = (char*)d_ws;
  const size_t MB = 1024 * 1024;
  ushortT* xb  = (ushortT*)(ws);             // 8 MB
  ushortT* wT  = (ushortT*)(ws + 8 * MB);    // 6 MB  (Wq|Wk|Wv col-major bf16)
  ushortT* woT = (ushortT*)(ws + 14 * MB);   // 2 MB
  ushortT* qw  = (ushortT*)(ws + 16 * MB);   // 8 MB  (B,H,T,D)
  ushortT* kw  = (ushortT*)(ws + 24 * MB);   // 8 MB  (B,H,T,D)
  ushortT* vtw = (ushortT*)(ws + 32 * MB);   // 8 MB  (B,H,D,T)
  ushortT* mg  = (ushortT*)(ws + 40 * MB);   // 8 MB  (B,T,H*D)

  conv_bf16<<<4096, 256, 0, stream>>>(x, xb);
  dim3 tb(32, 8);
  transp_bf16<<<dim3(32, 32), tb, 0, stream>>>(Wq, wT);
  transp_bf16<<<dim3(32, 32), tb, 0, stream>>>(Wk, wT + 1024 * 1024);
  transp_bf16<<<dim3(32, 32), tb, 0, stream>>>(Wv, wT + 2 * 1024 * 1024);
  transp_bf16<<<dim3(32, 32), tb, 0, stream>>>(Wo, woT);

  gemm_bt<0><<<dim3(24, 32), 256, 0, stream>>>(xb, wT, qw, kw, vtw, nullptr);

  attn_fused<<<dim3(64, 16, 2), 512, 0, stream>>>(qw, kw, vtw, s_prev, alpha, gamma,
                                                  beta, raw, mg);

  gemm_bt<1><<<dim3(8, 32), 256, 0, stream>>>(mg, woT, nullptr, nullptr, nullptr, out);
}

// Round 2
// 419.028 us; speedup vs baseline: 1.2881x; 1.2881x over previous
//
#include <hip/hip_runtime.h>

typedef __attribute__((ext_vector_type(4))) float f32x4;
typedef __attribute__((ext_vector_type(8))) short s16x8;
typedef __attribute__((ext_vector_type(4))) unsigned short u16x4;
typedef unsigned short ushortT;

__device__ inline ushortT f2bf(float f) {
  union { float f; unsigned u; } v; v.f = f;
  unsigned r = v.u + 0x7fffu + ((v.u >> 16) & 1u);
  return (ushortT)(r >> 16);
}
__device__ inline float bf2f(ushortT s) {
  union { unsigned u; float f; } v; v.u = ((unsigned)s) << 16;
  return v.f;
}
__device__ inline f32x4 mfma16(s16x8 a, s16x8 b, f32x4 c) {
  return __builtin_amdgcn_mfma_f32_16x16x32_bf16(a, b, c, 0, 0, 0);
}
typedef const __attribute__((address_space(1))) unsigned GU;
typedef __attribute__((address_space(3))) unsigned LU;
__device__ inline void gload_lds16(const void* g, void* l) {
  __builtin_amdgcn_global_load_lds((GU*)g, (LU*)l, 16, 0, 0);
}

// ---------------- prep kernels ----------------
__global__ void conv_bf16(const float* __restrict__ in, ushortT* __restrict__ o) {
  size_t i = ((size_t)blockIdx.x * 256 + threadIdx.x) * 4;
  f32x4 v = *(const f32x4*)(in + i);
  u16x4 u = { f2bf(v[0]), f2bf(v[1]), f2bf(v[2]), f2bf(v[3]) };
  *(u16x4*)(o + i) = u;
}

__global__ void transp_bf16(const float* __restrict__ Wm, ushortT* __restrict__ wt) {
  __shared__ float t[32][33];
  int bx = blockIdx.x, by = blockIdx.y;
  int x = threadIdx.x, y = threadIdx.y;
#pragma unroll
  for (int i = 0; i < 32; i += 8)
    t[y + i][x] = Wm[(size_t)(by * 32 + y + i) * 1024 + bx * 32 + x];
  __syncthreads();
#pragma unroll
  for (int i = 0; i < 32; i += 8)
    wt[(size_t)(bx * 32 + y + i) * 1024 + by * 32 + x] = f2bf(t[x][y + i]);
}

// ---------------- GEMM (C = A @ Bt^T), A:[M,1024] bf16, Bt:[N,1024] bf16 ----------------
template <int MODE>
__global__ __launch_bounds__(256) void gemm_bt(const ushortT* __restrict__ A,
                                               const ushortT* __restrict__ Bt,
                                               ushortT* __restrict__ o0,
                                               ushortT* __restrict__ o1,
                                               ushortT* __restrict__ o2,
                                               float* __restrict__ of) {
  __shared__ ushortT lA[128 * 32];
  __shared__ ushortT lB[128 * 32];
  const int tid = threadIdx.x;
  const int w = tid >> 6, l = tid & 63;
  const int a = l & 15, hi = l >> 4;
  const int wr = w >> 1, wc = w & 1;
  const int row0 = blockIdx.y * 128, col0 = blockIdx.x * 128;
  f32x4 acc[4][4] = {};
  const int r1 = tid >> 2, c1 = tid & 3;
  const int r2 = (tid + 256) >> 2, c2 = (tid + 256) & 3;
  for (int k0 = 0; k0 < 1024; k0 += 32) {
    __syncthreads();
    gload_lds16(A + (size_t)(row0 + r1) * 1024 + k0 + c1 * 8, &lA[r1 * 32 + c1 * 8]);
    gload_lds16(A + (size_t)(row0 + r2) * 1024 + k0 + c2 * 8, &lA[r2 * 32 + c2 * 8]);
    gload_lds16(Bt + (size_t)(col0 + r1) * 1024 + k0 + c1 * 8, &lB[r1 * 32 + c1 * 8]);
    gload_lds16(Bt + (size_t)(col0 + r2) * 1024 + k0 + c2 * 8, &lB[r2 * 32 + c2 * 8]);
    __syncthreads();
    s16x8 af[4], bfr[4];
#pragma unroll
    for (int m = 0; m < 4; ++m)
      af[m] = *(const s16x8*)&lA[(wr * 64 + m * 16 + a) * 32 + hi * 8];
#pragma unroll
    for (int n = 0; n < 4; ++n)
      bfr[n] = *(const s16x8*)&lB[(wc * 64 + n * 16 + a) * 32 + hi * 8];
#pragma unroll
    for (int m = 0; m < 4; ++m)
#pragma unroll
      for (int n = 0; n < 4; ++n)
        acc[m][n] = mfma16(af[m], bfr[n], acc[m][n]);
  }
  const int proj = col0 >> 10;
#pragma unroll
  for (int m = 0; m < 4; ++m)
#pragma unroll
    for (int n = 0; n < 4; ++n) {
      const int gr0 = row0 + wr * 64 + m * 16 + hi * 4;
      const int gc = col0 + wc * 64 + n * 16 + a;
#pragma unroll
      for (int r = 0; r < 4; ++r) {
        const int gr = gr0 + r;
        float v = acc[m][n][r];
        if (MODE == 0) {
          const int bb = gr >> 11, t = gr & 2047;
          const int cc = gc & 1023;
          const int hh = cc >> 6, d = cc & 63;
          const size_t bh = (size_t)bb * 16 + hh;
          if (proj == 0)      o0[(bh * 2048 + t) * 64 + d] = f2bf(v * 0.125f);
          else if (proj == 1) o1[(bh * 2048 + t) * 64 + d] = f2bf(v);
          else                o2[(bh * 64 + d) * 2048 + t] = f2bf(v);
        } else {
          of[(size_t)gr * 1024 + gc] = v;
        }
      }
    }
}

// ---------------- fused attention (16 query rows / block, 2 blocks/CU) ----------------
#define SBS 2056
__global__ __launch_bounds__(512) void attn_fused(
    const ushortT* __restrict__ qw, const ushortT* __restrict__ kw,
    const ushortT* __restrict__ vtw, const float* __restrict__ sprev,
    const float* __restrict__ alpha, const float* __restrict__ gamma,
    const float* __restrict__ beta, float* __restrict__ raw,
    ushortT* __restrict__ merged) {
  __shared__ ushortT sb[16 * SBS];
  __shared__ float mu_s[16], rs_s[16], li_s[16];
  __shared__ float red[4][64][4];
  const int t0 = blockIdx.x * 16;
  const int h = blockIdx.y, b = blockIdx.z;
  const int bh = b * 16 + h;
  const int tid = threadIdx.x;
  const int w = tid >> 6, l = tid & 63;
  const int a = l & 15, hi = l >> 4;

  // Q fragments for rows t0+a (Q pre-scaled by 1/8)
  const ushortT* qrow = qw + ((size_t)bh * 2048 + t0 + a) * 64;
  s16x8 qf0 = *(const s16x8*)(qrow + hi * 8);
  s16x8 qf1 = *(const s16x8*)(qrow + 32 + hi * 8);

  // phase 1: stream s_prev strip into LDS (bf16) + row stats (2 rows/wave)
  const float* sp = sprev + ((size_t)bh * 2048 + t0) * 2048;
#pragma unroll
  for (int rr = 0; rr < 2; ++rr) {
    const int row = 2 * w + rr;
    const float* rp = sp + (size_t)row * 2048 + 4 * l;
    float sum = 0.f, sq = 0.f;
#pragma unroll
    for (int i = 0; i < 8; ++i) {
      f32x4 v = *(const f32x4*)(rp + 256 * i);
      sum += v[0] + v[1] + v[2] + v[3];
      sq += v[0] * v[0] + v[1] * v[1] + v[2] * v[2] + v[3] * v[3];
      u16x4 u = { f2bf(v[0]), f2bf(v[1]), f2bf(v[2]), f2bf(v[3]) };
      *(u16x4*)&sb[row * SBS + 4 * l + 256 * i] = u;
    }
#pragma unroll
    for (int s = 32; s >= 1; s >>= 1) {
      sum += __shfl_xor(sum, s);
      sq += __shfl_xor(sq, s);
    }
    if (l == 0) {
      float mu = sum * (1.f / 2048.f);
      float var = fmaxf(sq * (1.f / 2048.f) - mu * mu, 0.f);
      mu_s[row] = mu;
      rs_s[row] = 1.f / (sqrtf(var) + 1e-5f);
    }
  }
  const float gate = 1.f / (1.f + __expf(-alpha[h]));
  const float gm = gamma[h], bt = beta[h];
  __syncthreads();

  // phase 2: QK^T + gated norm add; write raw; masked scores -> LDS
  float mu4[4], rs4[4];
#pragma unroll
  for (int r = 0; r < 4; ++r) {
    mu4[r] = mu_s[4 * hi + r];
    rs4[r] = rs_s[4 * hi + r];
  }
  const ushortT* kb = kw + (size_t)bh * 2048 * 64;
  float* rawb = raw + ((size_t)bh * 2048 + t0) * 2048;
  for (int i = 0; i < 16; ++i) {
    const int col0 = (w + 8 * i) * 16;
    const ushortT* kr = kb + (size_t)(col0 + a) * 64 + hi * 8;
    s16x8 kf0 = *(const s16x8*)(kr);
    s16x8 kf1 = *(const s16x8*)(kr + 32);
    f32x4 s4 = {};
    s4 = mfma16(qf0, kf0, s4);
    s4 = mfma16(qf1, kf1, s4);
#pragma unroll
    for (int r = 0; r < 4; ++r) {
      const int rl = 4 * hi + r;
      const float spv = bf2f(sb[rl * SBS + col0 + a]);
      const float rv = s4[r] + gate * (gm * (spv - mu4[r]) * rs4[r] + bt);
      rawb[(size_t)rl * 2048 + col0 + a] = rv;
      sb[rl * SBS + col0 + a] = f2bf((col0 + a) <= (t0 + rl) ? rv : -1e30f);
    }
  }
  __syncthreads();

  // phase 3: full-row softmax (2 rows/wave), overwrite LDS with exp(S-m) bf16
#pragma unroll
  for (int rr = 0; rr < 2; ++rr) {
    const int row = 2 * w + rr;
    float vals[32];
#pragma unroll
    for (int i = 0; i < 16; ++i) {
      unsigned u = *(const unsigned*)&sb[row * SBS + 2 * l + 128 * i];
      union { unsigned u; float f; } lo, hh;
      lo.u = u << 16; hh.u = u & 0xffff0000u;
      vals[2 * i] = lo.f; vals[2 * i + 1] = hh.f;
    }
    float m = -3e38f;
#pragma unroll
    for (int j = 0; j < 32; ++j) m = fmaxf(m, vals[j]);
#pragma unroll
    for (int s = 32; s >= 1; s >>= 1) m = fmaxf(m, __shfl_xor(m, s));
    float sum = 0.f;
#pragma unroll
    for (int j = 0; j < 32; ++j) { vals[j] = __expf(vals[j] - m); sum += vals[j]; }
#pragma unroll
    for (int s = 32; s >= 1; s >>= 1) sum += __shfl_xor(sum, s);
#pragma unroll
    for (int i = 0; i < 16; ++i) {
      unsigned u = (unsigned)f2bf(vals[2 * i]) | ((unsigned)f2bf(vals[2 * i + 1]) << 16);
      *(unsigned*)&sb[row * SBS + 2 * l + 128 * i] = u;
    }
    if (l == 0) li_s[row] = 1.f / sum;
  }
  __syncthreads();

  // phase 4: PV. 4 col-tiles (n), K-range split across wave pairs (half).
  const int n = w & 3, half = w >> 2;
  const ushortT* vb = vtw + ((size_t)bh * 64 + 16 * n + a) * 2048;
  f32x4 acc = {};
  const int nch = (t0 + 47) >> 5;
  for (int c = half; c < nch; c += 2) {
    s16x8 pf = *(const s16x8*)&sb[a * SBS + 32 * c + 8 * hi];
    s16x8 vf = *(const s16x8*)(vb + 32 * c + 8 * hi);
    acc = mfma16(pf, vf, acc);
  }
  if (half == 1) *(f32x4*)red[n][l] = acc;
  __syncthreads();
  if (half == 0) {
    f32x4 o = *(f32x4*)red[n][l];
    acc += o;
#pragma unroll
    for (int r = 0; r < 4; ++r) {
      const int rl = 4 * hi + r;
      const float cx = acc[r] * li_s[rl];
      merged[((size_t)b * 2048 + t0 + rl) * 1024 + h * 64 + 16 * n + a] = f2bf(cx);
    }
  }
}

extern "C" void kernel_launch(void* const* d_in, const int* in_sizes, int n_in,
                              void* d_out, int out_size, void* d_ws, size_t ws_size,
                              hipStream_t stream) {
  (void)in_sizes; (void)n_in; (void)out_size; (void)ws_size;
  const float* x      = (const float*)d_in[0];
  const float* s_prev = (const float*)d_in[1];
  const float* Wq     = (const float*)d_in[2];
  const float* Wk     = (const float*)d_in[3];
  const float* Wv     = (const float*)d_in[4];
  const float* Wo     = (const float*)d_in[5];
  const float* alpha  = (const float*)d_in[6];
  const float* gamma  = (const float*)d_in[7];
  const float* beta   = (const float*)d_in[8];

  float* out = (float*)d_out;
  float* raw = out + (size_t)4194304;  // B*T*HID

  char* ws = (char*)d_ws;
  const size_t MB = 1024 * 1024;
  ushortT* xb  = (ushortT*)(ws);             // 8 MB
  ushortT* wT  = (ushortT*)(ws + 8 * MB);    // 6 MB  (Wq|Wk|Wv col-major bf16)
  ushortT* woT = (ushortT*)(ws + 14 * MB);   // 2 MB
  ushortT* qw  = (ushortT*)(ws + 16 * MB);   // 8 MB  (B,H,T,D)
  ushortT* kw  = (ushortT*)(ws + 24 * MB);   // 8 MB  (B,H,T,D)
  ushortT* vtw = (ushortT*)(ws + 32 * MB);   // 8 MB  (B,H,D,T)
  ushortT* mg  = (ushortT*)(ws + 40 * MB);   // 8 MB  (B,T,H*D)

  conv_bf16<<<4096, 256, 0, stream>>>(x, xb);
  dim3 tb(32, 8);
  transp_bf16<<<dim3(32, 32), tb, 0, stream>>>(Wq, wT);
  transp_bf16<<<dim3(32, 32), tb, 0, stream>>>(Wk, wT + 1024 * 1024);
  transp_bf16<<<dim3(32, 32), tb, 0, stream>>>(Wv, wT + 2 * 1024 * 1024);
  transp_bf16<<<dim3(32, 32), tb, 0, stream>>>(Wo, woT);

  gemm_bt<0><<<dim3(24, 32), 256, 0, stream>>>(xb, wT, qw, kw, vtw, nullptr);

  attn_fused<<<dim3(128, 16, 2), 512, 0, stream>>>(qw, kw, vtw, s_prev, alpha, gamma,
                                                   beta, raw, mg);

  gemm_bt<1><<<dim3(8, 32), 256, 0, stream>>>(mg, woT, nullptr, nullptr, nullptr, out);
}